// Round 15
// baseline (55.660 us; speedup 1.0000x reference)
//
#include <hip/hip_runtime.h>

#define F_IN    32768
#define HID     64
#define NB_OBJ  16
#define BATCH   64
#define N_AGENTS 4
#define N_ACT   13
#define NEG_SLOPE 0.01f

#define FC      64               // f-chunk width per fused block
#define NCHUNK  (F_IN / FC)      // 512 split-K chunks
#define RG      8                // reduce blocks per batch

typedef float f32x4 __attribute__((ext_vector_type(4)));

// static scratch:
// g_part [BATCH][NCHUNK][HID] = 8 MiB  (split-K partials, [b][chunk][h])
// g_red  [BATCH][RG][HID]     = 128 KiB (per-slice sums)
// g_cnt  [BATCH]              arrival counters (accumulate across replays;
//                              winner test uses % RG so init value is irrelevant)
__device__ float    g_part[BATCH * NCHUNK * HID];
__device__ float    g_red[BATCH * RG * HID];
__device__ unsigned g_cnt[BATCH];

// ---------------------------------------------------------------------------
// K1: fused node-mean + partial GEMM (proven R11/R14 body, [b][chunk][h]
// store). grid = NCHUNK (512), block = 512 (8 waves).
// ---------------------------------------------------------------------------
__global__ __launch_bounds__(512, 4)
void k_fused(const float* __restrict__ u, const float* __restrict__ w) {
    __shared__ float xbar[BATCH][FC + 4];   // row pitch 68 floats
    const int t    = threadIdx.x;
    const int blk  = blockIdx.x;
    const int f0   = blk * FC;
    const int lane = t & 63;
    const int wv   = t >> 6;                // 0..7

    float wreg[FC];
    {
        const float* wp = w + (size_t)f0 * HID + lane;
        #pragma unroll
        for (int f = 0; f < FC; ++f) wreg[f] = wp[f * HID];
    }

    // step A: xbar[b][f] = (1/16) * sum_o u[b][o][f0+f]
    {
        const int b = t >> 3;
        const int j = t & 7;
        const float* up = u + (size_t)b * (NB_OBJ * F_IN) + f0 + j * 4;
        f32x4 a0 = (f32x4)(0.f);
        f32x4 a1 = (f32x4)(0.f);
        #pragma unroll
        for (int o = 0; o < NB_OBJ; ++o) {
            const float* ro = up + (size_t)o * F_IN;
            a0 += *reinterpret_cast<const f32x4*>(ro);
            a1 += *reinterpret_cast<const f32x4*>(ro + 32);
        }
        const float inv = 1.0f / (float)NB_OBJ;
        a0 *= inv;
        a1 *= inv;
        *reinterpret_cast<f32x4*>(&xbar[b][j * 4])      = a0;
        *reinterpret_cast<f32x4*>(&xbar[b][32 + j * 4]) = a1;
    }
    __syncthreads();

    // step B: wave -> 8 batches; lane = h; store [b][blk][h] (256B/row).
    {
        #pragma unroll
        for (int bb = 0; bb < 8; ++bb) {
            const int b = wv * 8 + bb;
            float acc = 0.f;
            #pragma unroll
            for (int fq = 0; fq < FC / 4; ++fq) {
                f32x4 xb = *reinterpret_cast<const f32x4*>(&xbar[b][fq * 4]);
                acc += xb.x * wreg[fq * 4 + 0];
                acc += xb.y * wreg[fq * 4 + 1];
                acc += xb.z * wreg[fq * 4 + 2];
                acc += xb.w * wreg[fq * 4 + 3];
            }
            g_part[((size_t)b * NCHUNK + blk) * HID + lane] = acc;
        }
    }
}

// ---------------------------------------------------------------------------
// K2: full-machine reduction + deterministic lookback heads.
// grid = BATCH*RG (512) blocks x 256 thr. Block (b, g) sums its contiguous
// 64-chunk slice -> g_red[b][g][*]; fence; atomicAdd(g_cnt[b]). The LAST
// arriver (old % RG == RG-1; works for any counter base, so replays are
// safe with no reset) acquires and finishes: pooled = gcn_b + sum_g g_red
// in FIXED g order (deterministic FP), then heads + argmax for batch b.
// ---------------------------------------------------------------------------
__global__ __launch_bounds__(256)
void k_tail(const float* __restrict__ gcn_b,
            const float* __restrict__ w1, const float* __restrict__ b1,
            const float* __restrict__ w2, const float* __restrict__ b2,
            const float* __restrict__ actions, float* __restrict__ out) {
    const int bid = blockIdx.x;
    const int b   = bid >> 3;        // batch
    const int g   = bid & 7;         // slice
    const int t   = threadIdx.x;
    const int h   = t & 63;
    const int kg  = t >> 6;          // 0..3

    __shared__ float red[4][HID];
    __shared__ float pooled[HID];
    __shared__ float zbuf[N_AGENTS][HID];
    __shared__ float qbuf[N_AGENTS][N_ACT];
    __shared__ int   winner;

    // reduce: 16 chunks per (kg,h) thread; contiguous 16KB per block.
    {
        const float* p = g_part + ((size_t)b * NCHUNK + g * 64 + kg * 16) * HID + h;
        float acc = 0.f;
        #pragma unroll
        for (int i = 0; i < 16; ++i)
            acc += p[(size_t)i * HID];
        red[kg][h] = acc;
    }
    __syncthreads();
    if (t < HID)
        g_red[((size_t)b * RG + g) * HID + t] =
            red[0][t] + red[1][t] + red[2][t] + red[3][t];

    // arrival (one thread); publish then count
    if (t == 0) {
        __threadfence();
        unsigned old = atomicAdd(&g_cnt[b], 1u);
        winner = ((old % RG) == RG - 1) ? 1 : 0;
    }
    __syncthreads();
    if (!winner) return;
    __threadfence();   // acquire: make all 8 slices' g_red visible

    // pooled[h] = gcn_b + sum_g g_red[b][g][h]  (fixed order)
    if (t < HID) {
        float acc = gcn_b[t];
        #pragma unroll
        for (int gg = 0; gg < RG; ++gg)
            acc += g_red[((size_t)b * RG + gg) * HID + t];
        pooled[t] = acc;
    }
    __syncthreads();

    // z[a][k] = leaky(b1 + sum_h pooled[h] * w1[a][h][k])
    {
        const int a = t >> 6, k = t & 63;
        const float* w1p = w1 + a * (HID * HID) + k;
        float acc = b1[a * HID + k];
        #pragma unroll
        for (int hh = 0; hh < HID; ++hh) acc += pooled[hh] * w1p[hh * HID];
        zbuf[a][k] = (acc >= 0.f) ? acc : NEG_SLOPE * acc;
    }
    __syncthreads();

    // q[a][c] = b2 + sum_h z[a][h] * w2[a][h][c]
    if (t < N_AGENTS * N_ACT) {
        const int a = t / N_ACT, c = t % N_ACT;
        const float* w2p = w2 + a * (HID * N_ACT) + c;
        float acc = b2[a * N_ACT + c];
        #pragma unroll
        for (int hh = 0; hh < HID; ++hh) acc += zbuf[a][hh] * w2p[hh * N_ACT];
        qbuf[a][c] = acc;
    }
    __syncthreads();

    // argmax over actions (first-max, matching jnp.argmax), gather
    if (t < N_AGENTS) {
        const float* ap = actions + ((size_t)t * BATCH + b) * N_ACT;
        int best = 0; float bv = ap[0];
        for (int c = 1; c < N_ACT; ++c) {
            float v = ap[c];
            if (v > bv) { bv = v; best = c; }
        }
        out[t * BATCH + b] = qbuf[t][best];
    }
}

extern "C" void kernel_launch(void* const* d_in, const int* in_sizes, int n_in,
                              void* d_out, int out_size, void* d_ws, size_t ws_size,
                              hipStream_t stream) {
    const float* u   = (const float*)d_in[0];
    // d_in[1] = binary_tensor: dead in the reference computation
    const float* act = (const float*)d_in[2];
    const float* gw  = (const float*)d_in[3];
    const float* gb  = (const float*)d_in[4];
    const float* w1  = (const float*)d_in[5];
    const float* b1  = (const float*)d_in[6];
    const float* w2  = (const float*)d_in[7];
    const float* b2  = (const float*)d_in[8];
    float* out = (float*)d_out;

    hipLaunchKernelGGL(k_fused, dim3(NCHUNK),     dim3(512), 0, stream, u, gw);
    hipLaunchKernelGGL(k_tail,  dim3(BATCH * RG), dim3(256), 0, stream,
                       gb, w1, b1, w2, b2, act, out);
}

// Round 16
// 37.323 us; speedup vs baseline: 1.4913x; 1.4913x over previous
//
#include <hip/hip_runtime.h>

#define F_IN    32768
#define HID     64
#define NB_OBJ  16
#define BATCH   64
#define N_AGENTS 4
#define N_ACT   13
#define NEG_SLOPE 0.01f

#define FC      128              // f-range per fused block (2 halves of 64)
#define NCHUNK  (F_IN / FC)      // 256 split-K chunks

typedef float f32x4 __attribute__((ext_vector_type(4)));

// static scratch: g_part[BATCH][NCHUNK][HID] = 4 MiB ([b][chunk][h])
__device__ float g_part[BATCH * NCHUNK * HID];

// ---------------------------------------------------------------------------
// K1: fused node-mean + partial GEMM, FC=128. grid = 256, block = 1024
// (16 waves -> 1 block/CU, 16 waves/CU, same occupancy as the FC=64 version).
// Step A: thread (b = t>>4, j = t&15) averages f-quads j and j+16 (nt loads).
// Step B: wave wv -> 4 batches; lane = h; wreg[64] reloaded per 64-f half.
// ---------------------------------------------------------------------------
__global__ __launch_bounds__(1024, 4)
void k_fused(const float* __restrict__ u, const float* __restrict__ w) {
    __shared__ float xbar[BATCH][FC + 4];   // row pitch 132 floats (33.8 KB)
    const int t    = threadIdx.x;
    const int blk  = blockIdx.x;
    const int f0   = blk * FC;
    const int lane = t & 63;
    const int wv   = t >> 6;                // 0..15

    // step A: xbar[b][f] = (1/16) * sum_o u[b][o][f0+f]
    {
        const int b = t >> 4;               // 0..63
        const int j = t & 15;               // 0..15
        const float* up = u + (size_t)b * (NB_OBJ * F_IN) + f0 + j * 4;
        f32x4 a0 = (f32x4)(0.f);
        f32x4 a1 = (f32x4)(0.f);
        #pragma unroll
        for (int o = 0; o < NB_OBJ; ++o) {
            const float* ro = up + (size_t)o * F_IN;
            a0 += __builtin_nontemporal_load(reinterpret_cast<const f32x4*>(ro));
            a1 += __builtin_nontemporal_load(reinterpret_cast<const f32x4*>(ro + 64));
        }
        const float inv = 1.0f / (float)NB_OBJ;
        a0 *= inv;
        a1 *= inv;
        *reinterpret_cast<f32x4*>(&xbar[b][j * 4])      = a0;
        *reinterpret_cast<f32x4*>(&xbar[b][64 + j * 4]) = a1;
    }
    __syncthreads();

    // step B: wave -> 4 batches; f ascending across the two halves.
    float acc[4] = {0.f, 0.f, 0.f, 0.f};
    #pragma unroll
    for (int sc = 0; sc < 2; ++sc) {
        // w column slice for this half: wreg[f] = w[(f0+sc*64+f)*HID + lane]
        float wreg[64];
        {
            const float* wp = w + (size_t)(f0 + sc * 64) * HID + lane;
            #pragma unroll
            for (int f = 0; f < 64; ++f) wreg[f] = wp[f * HID];
        }
        #pragma unroll
        for (int bb = 0; bb < 4; ++bb) {
            const int b = wv * 4 + bb;
            float a = 0.f;
            #pragma unroll
            for (int fq = 0; fq < 16; ++fq) {
                f32x4 xb = *reinterpret_cast<const f32x4*>(&xbar[b][sc * 64 + fq * 4]);
                a += xb.x * wreg[fq * 4 + 0];
                a += xb.y * wreg[fq * 4 + 1];
                a += xb.z * wreg[fq * 4 + 2];
                a += xb.w * wreg[fq * 4 + 3];
            }
            acc[bb] += a;
        }
    }
    #pragma unroll
    for (int bb = 0; bb < 4; ++bb) {
        const int b = wv * 4 + bb;
        g_part[((size_t)b * NCHUNK + blk) * HID + lane] = acc[bb];
    }
}

// ---------------------------------------------------------------------------
// K2: merged tail. grid = BATCH (64), block = 1024 (16 waves).
// phase 1: (kg = t>>6, h = t&63) sums 16 contiguous chunks (4KB each).
// ---------------------------------------------------------------------------
__global__ __launch_bounds__(1024)
void k_tail(const float* __restrict__ gcn_b,
            const float* __restrict__ w1, const float* __restrict__ b1,
            const float* __restrict__ w2, const float* __restrict__ b2,
            const float* __restrict__ actions, float* __restrict__ out) {
    const int b = blockIdx.x;
    const int t = threadIdx.x;
    __shared__ float red[16][HID];
    __shared__ float pooled[HID];
    __shared__ float zbuf[N_AGENTS][HID];
    __shared__ float qbuf[N_AGENTS][N_ACT];

    // phase 1: red[kg][h] = sum of this kg's 16 chunks
    {
        const int h  = t & 63;
        const int kg = t >> 6;   // 0..15
        const float* p = g_part + ((size_t)b * NCHUNK + kg * 16) * HID + h;
        float acc = 0.f;
        #pragma unroll
        for (int i = 0; i < 16; ++i)
            acc += p[(size_t)i * HID];
        red[kg][h] = acc;
    }
    __syncthreads();
    if (t < HID) {
        float acc = gcn_b[t];
        #pragma unroll
        for (int kg = 0; kg < 16; ++kg) acc += red[kg][t];
        pooled[t] = acc;
    }
    __syncthreads();

    // phase 2: z[a][k] = leaky(b1 + sum_h pooled[h] * w1[a][h][k])
    if (t < N_AGENTS * HID) {
        const int a = t >> 6, k = t & 63;
        const float* w1p = w1 + a * (HID * HID) + k;
        float acc = b1[a * HID + k];
        #pragma unroll
        for (int hh = 0; hh < HID; ++hh) acc += pooled[hh] * w1p[hh * HID];
        zbuf[a][k] = (acc >= 0.f) ? acc : NEG_SLOPE * acc;
    }
    __syncthreads();

    // phase 3: q[a][c] = b2 + sum_h z[a][h] * w2[a][h][c]
    if (t < N_AGENTS * N_ACT) {
        const int a = t / N_ACT, c = t % N_ACT;
        const float* w2p = w2 + a * (HID * N_ACT) + c;
        float acc = b2[a * N_ACT + c];
        #pragma unroll
        for (int hh = 0; hh < HID; ++hh) acc += zbuf[a][hh] * w2p[hh * N_ACT];
        qbuf[a][c] = acc;
    }
    __syncthreads();

    // phase 4: argmax over actions (first-max, matching jnp.argmax), gather
    if (t < N_AGENTS) {
        const float* ap = actions + ((size_t)t * BATCH + b) * N_ACT;
        int best = 0; float bv = ap[0];
        for (int c = 1; c < N_ACT; ++c) {
            float v = ap[c];
            if (v > bv) { bv = v; best = c; }
        }
        out[t * BATCH + b] = qbuf[t][best];
    }
}

extern "C" void kernel_launch(void* const* d_in, const int* in_sizes, int n_in,
                              void* d_out, int out_size, void* d_ws, size_t ws_size,
                              hipStream_t stream) {
    const float* u   = (const float*)d_in[0];
    // d_in[1] = binary_tensor: dead in the reference computation
    const float* act = (const float*)d_in[2];
    const float* gw  = (const float*)d_in[3];
    const float* gb  = (const float*)d_in[4];
    const float* w1  = (const float*)d_in[5];
    const float* b1  = (const float*)d_in[6];
    const float* w2  = (const float*)d_in[7];
    const float* b2  = (const float*)d_in[8];
    float* out = (float*)d_out;

    hipLaunchKernelGGL(k_fused, dim3(NCHUNK), dim3(1024), 0, stream, u, gw);
    hipLaunchKernelGGL(k_tail,  dim3(BATCH),  dim3(1024), 0, stream,
                       gb, w1, b1, w2, b2, act, out);
}